// Round 1
// baseline (18440.849 us; speedup 1.0000x reference)
//
#include <hip/hip_runtime.h>
#include <math.h>

// Problem dims
#define T_STEPS 1024
#define BATCH   128
#define D_IN    256
#define H_DIM   256
#define K_DIM   512   // D+H
#define NCOL    1024  // 4 gates * H

__device__ __forceinline__ float sigmoidf_(float x) {
    return 1.0f / (1.0f + __expf(-x));
}

// tanh via exp of negative magnitude: no overflow, ~1e-6 accuracy
__device__ __forceinline__ float tanhf_(float x) {
    float ax = fabsf(x);
    float t = __expf(-2.0f * ax);
    float r = (1.0f - t) / (1.0f + t);
    return copysignf(r, x);
}

// Build WT[k][j] (k in [0,512), j = gate*256 + h) from the four [256,512] row-major
// gate weight matrices, plus the combined bias vector biasc[1024].
__global__ void prep_kernel(const float* __restrict__ Wf, const float* __restrict__ Wi,
                            const float* __restrict__ Wg, const float* __restrict__ Wo,
                            const float* __restrict__ bf, const float* __restrict__ bi,
                            const float* __restrict__ bg, const float* __restrict__ bo,
                            float* __restrict__ WT, float* __restrict__ biasc) {
    int idx = blockIdx.x * 256 + threadIdx.x;      // 0 .. 512*1024-1
    int j = idx & (NCOL - 1);
    int k = idx >> 10;
    int g = j >> 8;
    int h = j & 255;
    const float* W = (g == 0) ? Wf : (g == 1) ? Wi : (g == 2) ? Wg : Wo;
    WT[idx] = W[h * K_DIM + k];
    if (idx < NCOL) {
        const float* bb = (g == 0) ? bf : (g == 1) ? bi : (g == 2) ? bg : bo;
        biasc[idx] = bb[h];
    }
}

// One workgroup per batch row; 256 threads; thread tid owns column h=tid of all
// four gates. Entire T-loop runs inside the kernel with only __syncthreads().
__global__ __launch_bounds__(256) void qlstm_kernel(
    const float* __restrict__ x,      // [T][B][256]
    const float* __restrict__ WT,     // [512][1024] transposed combined weights
    const float* __restrict__ biasc,  // [1024]
    const float* __restrict__ estW1,  // [4][8][256]
    const float* __restrict__ estb1,  // [4][8]
    const float* __restrict__ estW2,  // [4][4][8]
    const float* __restrict__ estb2,  // [4][4]
    const float* __restrict__ estW3,  // [4][1][4]
    const float* __restrict__ estb3,  // [4][1]
    float* __restrict__ out)          // [T][B][256] ++ hx[B][256] ++ cx[B][256]
{
    __shared__ float comb[K_DIM];        // [x(t) | hx]
    __shared__ float gates[4][H_DIM];    // activated gate values (pre est-scale)
    __shared__ float w1[4][8][H_DIM];    // estW1, 32 KB
    __shared__ float sb1[32];            // estb1
    __shared__ float sW2[128];           // estW2
    __shared__ float sb2[16];            // estb2
    __shared__ float sW3[16];            // estW3
    __shared__ float sb3[4];             // estb3
    __shared__ float escale[4];

    const int b   = blockIdx.x;
    const int tid = threadIdx.x;

    // stage est params into LDS
    for (int i = tid; i < 4 * 8 * H_DIM; i += 256) ((float*)w1)[i] = estW1[i];
    if (tid < 32)  sb1[tid] = estb1[tid];
    if (tid < 128) sW2[tid] = estW2[tid];
    if (tid < 16)  sb2[tid] = estb2[tid];
    if (tid < 16)  sW3[tid] = estW3[tid];
    if (tid < 4)   sb3[tid] = estb3[tid];

    float c_reg = 0.0f;                  // cx[b][tid]
    comb[H_DIM + tid] = 0.0f;            // hx = 0

    const float bi0 = biasc[tid];
    const float bi1 = biasc[256 + tid];
    const float bi2 = biasc[512 + tid];
    const float bi3 = biasc[768 + tid];

    const float* xp = x + (size_t)b * D_IN + tid;
    float*       op = out + (size_t)b * H_DIM + tid;

    float h_reg = 0.0f;
    __syncthreads();

    for (int t = 0; t < T_STEPS; t++) {
        // load x(t) slice for this row (coalesced 1 KB)
        comb[tid] = xp[(size_t)t * BATCH * D_IN];
        __syncthreads();

        // gate matmul: 4 columns per thread, K=512, weights streamed from L2
        float a0 = bi0, a1 = bi1, a2 = bi2, a3 = bi3;
        const float* wp = WT + tid;
        #pragma unroll 2
        for (int k = 0; k < K_DIM; k += 4) {
            float4 cv = *(const float4*)(comb + k);
            a0 = fmaf(cv.x, wp[0], a0);
            a1 = fmaf(cv.x, wp[256], a1);
            a2 = fmaf(cv.x, wp[512], a2);
            a3 = fmaf(cv.x, wp[768], a3);
            wp += NCOL;
            a0 = fmaf(cv.y, wp[0], a0);
            a1 = fmaf(cv.y, wp[256], a1);
            a2 = fmaf(cv.y, wp[512], a2);
            a3 = fmaf(cv.y, wp[768], a3);
            wp += NCOL;
            a0 = fmaf(cv.z, wp[0], a0);
            a1 = fmaf(cv.z, wp[256], a1);
            a2 = fmaf(cv.z, wp[512], a2);
            a3 = fmaf(cv.z, wp[768], a3);
            wp += NCOL;
            a0 = fmaf(cv.w, wp[0], a0);
            a1 = fmaf(cv.w, wp[256], a1);
            a2 = fmaf(cv.w, wp[512], a2);
            a3 = fmaf(cv.w, wp[768], a3);
            wp += NCOL;
        }

        const float vf = sigmoidf_(a0);
        const float vi = sigmoidf_(a1);
        const float vg = tanhf_(a2);
        const float vo = sigmoidf_(a3);
        gates[0][tid] = vf;
        gates[1][tid] = vi;
        gates[2][tid] = vg;
        gates[3][tid] = vo;
        __syncthreads();

        // est MLP: wave w (tid>>6) handles gate w.  H->8 (wave-reduced) ->4 ->1
        {
            const int w    = tid >> 6;
            const int lane = tid & 63;
            float h1[8];
            #pragma unroll
            for (int j = 0; j < 8; j++) {
                const float* wrow = &w1[w][j][0];
                float s = gates[w][lane]       * wrow[lane]
                        + gates[w][lane + 64]  * wrow[lane + 64]
                        + gates[w][lane + 128] * wrow[lane + 128]
                        + gates[w][lane + 192] * wrow[lane + 192];
                #pragma unroll
                for (int m = 1; m < 64; m <<= 1) s += __shfl_xor(s, m, 64);
                h1[j] = tanhf_(s + sb1[w * 8 + j]);
            }
            float h2[4];
            #pragma unroll
            for (int j = 0; j < 4; j++) {
                float s = sb2[w * 4 + j];
                #pragma unroll
                for (int q = 0; q < 8; q++) s = fmaf(h1[q], sW2[w * 32 + j * 8 + q], s);
                h2[j] = tanhf_(s);
            }
            float s3 = sb3[w];
            #pragma unroll
            for (int q = 0; q < 4; q++) s3 = fmaf(h2[q], sW3[w * 4 + q], s3);
            if (lane == 0) escale[w] = sigmoidf_(s3);
        }
        __syncthreads();

        // elementwise state update (thread tid owns h=tid)
        const float f  = vf * escale[0];
        const float ii = vi * escale[1];
        const float g  = vg * escale[2];
        const float o  = vo * escale[3];
        c_reg = f * c_reg + ii * g;
        h_reg = o * tanhf_(c_reg);
        comb[H_DIM + tid] = h_reg;                 // hx for next step
        op[(size_t)t * BATCH * H_DIM] = h_reg;     // stacked output
        // next iteration's top __syncthreads makes comb update visible
    }

    // final hx, cx
    const size_t stacked = (size_t)T_STEPS * BATCH * H_DIM;
    out[stacked + (size_t)b * H_DIM + tid] = h_reg;
    out[stacked + (size_t)BATCH * H_DIM + (size_t)b * H_DIM + tid] = c_reg;
}

extern "C" void kernel_launch(void* const* d_in, const int* in_sizes, int n_in,
                              void* d_out, int out_size, void* d_ws, size_t ws_size,
                              hipStream_t stream) {
    const float* x     = (const float*)d_in[0];
    const float* Wf    = (const float*)d_in[1];
    const float* bf    = (const float*)d_in[2];
    const float* Wi    = (const float*)d_in[3];
    const float* bi    = (const float*)d_in[4];
    const float* Wg    = (const float*)d_in[5];
    const float* bg    = (const float*)d_in[6];
    const float* Wo    = (const float*)d_in[7];
    const float* bo    = (const float*)d_in[8];
    const float* estW1 = (const float*)d_in[9];
    const float* estb1 = (const float*)d_in[10];
    const float* estW2 = (const float*)d_in[11];
    const float* estb2 = (const float*)d_in[12];
    const float* estW3 = (const float*)d_in[13];
    const float* estb3 = (const float*)d_in[14];

    float* WT    = (float*)d_ws;                 // 512*1024 floats = 2 MB
    float* biasc = WT + (size_t)K_DIM * NCOL;    // 1024 floats

    prep_kernel<<<(K_DIM * NCOL) / 256, 256, 0, stream>>>(Wf, Wi, Wg, Wo, bf, bi, bg, bo,
                                                          WT, biasc);
    qlstm_kernel<<<BATCH, 256, 0, stream>>>(x, WT, biasc, estW1, estb1, estW2, estb2,
                                            estW3, estb3, (float*)d_out);
}

// Round 2
// 13520.619 us; speedup vs baseline: 1.3639x; 1.3639x over previous
//
#include <hip/hip_runtime.h>
#include <hip/hip_fp16.h>
#include <math.h>

// Problem dims
#define T_STEPS 1024
#define BATCH   128
#define D_IN    256
#define H_DIM   256
#define NCOL    1024  // 4 gates * H

__device__ __forceinline__ float sigmoidf_(float x) {
    return 1.0f / (1.0f + __expf(-x));
}

__device__ __forceinline__ float tanhf_(float x) {
    float ax = fabsf(x);
    float t = __expf(-2.0f * ax);
    float r = (1.0f - t) / (1.0f + t);
    return copysignf(r, x);
}

// 8 f16 MACs: wv = 4 half2 (cols j0..j0+3, k-pair), cv = comb[2k2..2k2+1]
#define MAC8(wv, cv)                                                        \
    do {                                                                    \
        __half2 q0 = *(__half2*)&(wv).x, q1 = *(__half2*)&(wv).y;           \
        __half2 q2 = *(__half2*)&(wv).z, q3 = *(__half2*)&(wv).w;           \
        a0 = fmaf((cv).x, __half2float(q0.x), a0);                          \
        a0 = fmaf((cv).y, __half2float(q0.y), a0);                          \
        a1 = fmaf((cv).x, __half2float(q1.x), a1);                          \
        a1 = fmaf((cv).y, __half2float(q1.y), a1);                          \
        a2 = fmaf((cv).x, __half2float(q2.x), a2);                          \
        a2 = fmaf((cv).y, __half2float(q2.y), a2);                          \
        a3 = fmaf((cv).x, __half2float(q3.x), a3);                          \
        a3 = fmaf((cv).y, __half2float(q3.y), a3);                          \
    } while (0)

// Build packed-f16 weight pair arrays:
//   WX2[k2*1024 + j] = half2(Wg[h][2k2], Wg[h][2k2+1])        (x part, k<256)
//   WH2[k2*1024 + j] = half2(Wg[h][256+2k2], Wg[h][256+2k2+1]) (hx part)
// with j = gate*256 + h.  Plus combined bias biasc[1024] (fp32).
__global__ void prep_kernel(const float* __restrict__ Wf, const float* __restrict__ Wi,
                            const float* __restrict__ Wg, const float* __restrict__ Wo,
                            const float* __restrict__ bf, const float* __restrict__ bi,
                            const float* __restrict__ bg, const float* __restrict__ bo,
                            unsigned int* __restrict__ WX2, unsigned int* __restrict__ WH2,
                            float* __restrict__ biasc) {
    int idx = blockIdx.x * 256 + threadIdx.x;   // 0 .. 128*1024-1
    int k2 = idx >> 10;
    int j  = idx & 1023;
    int g  = j >> 8;
    int h  = j & 255;
    const float* W = (g == 0) ? Wf : (g == 1) ? Wi : (g == 2) ? Wg : Wo;
    const float* row = W + h * 512;
    __half2 px = __floats2half2_rn(row[2 * k2], row[2 * k2 + 1]);
    __half2 ph = __floats2half2_rn(row[256 + 2 * k2], row[256 + 2 * k2 + 1]);
    WX2[idx] = *(unsigned int*)&px;
    WH2[idx] = *(unsigned int*)&ph;
    if (idx < NCOL) {
        const float* bb = (g == 0) ? bf : (g == 1) ? bi : (g == 2) ? bg : bo;
        biasc[idx] = bb[h];
    }
}

// pre[r][j] = bias[j] + sum_d x[r][d]*Wx[j][d], r = t*B+b (fully parallel GEMM)
// One WG per 16 rows; thread tid owns cols 4*tid..4*tid+3.
__global__ __launch_bounds__(256) void pregemm_kernel(
    const float* __restrict__ x, const unsigned int* __restrict__ WX2,
    const float* __restrict__ biasc, float* __restrict__ pre) {
    __shared__ float xs[16 * 256];   // 16 KB x tile
    const int tid = threadIdx.x;
    const size_t r0 = (size_t)blockIdx.x * 16;

    // stage 16 rows of x (coalesced float4)
    {
        const float4* xsrc = (const float4*)(x + r0 * D_IN);
        float4* xd = (float4*)xs;
        #pragma unroll
        for (int i = 0; i < 4; i++) xd[tid + 256 * i] = xsrc[tid + 256 * i];
    }
    float4 b4 = ((const float4*)biasc)[tid];
    float a[16][4];
    #pragma unroll
    for (int r = 0; r < 16; r++) {
        a[r][0] = b4.x; a[r][1] = b4.y; a[r][2] = b4.z; a[r][3] = b4.w;
    }
    __syncthreads();

    const uint4* wp = (const uint4*)WX2;
    const float2* xs2 = (const float2*)xs;
    #pragma unroll 2
    for (int k2 = 0; k2 < 128; k2++) {
        uint4 wv = wp[k2 * 256 + tid];
        __half2 q0 = *(__half2*)&wv.x, q1 = *(__half2*)&wv.y;
        __half2 q2 = *(__half2*)&wv.z, q3 = *(__half2*)&wv.w;
        float w0l = __half2float(q0.x), w0h = __half2float(q0.y);
        float w1l = __half2float(q1.x), w1h = __half2float(q1.y);
        float w2l = __half2float(q2.x), w2h = __half2float(q2.y);
        float w3l = __half2float(q3.x), w3h = __half2float(q3.y);
        #pragma unroll
        for (int r = 0; r < 16; r++) {
            float2 xv = xs2[r * 128 + k2];
            a[r][0] = fmaf(xv.x, w0l, a[r][0]); a[r][0] = fmaf(xv.y, w0h, a[r][0]);
            a[r][1] = fmaf(xv.x, w1l, a[r][1]); a[r][1] = fmaf(xv.y, w1h, a[r][1]);
            a[r][2] = fmaf(xv.x, w2l, a[r][2]); a[r][2] = fmaf(xv.y, w2h, a[r][2]);
            a[r][3] = fmaf(xv.x, w3l, a[r][3]); a[r][3] = fmaf(xv.y, w3h, a[r][3]);
        }
    }
    #pragma unroll
    for (int r = 0; r < 16; r++) {
        ((float4*)(pre + (r0 + r) * NCOL))[tid] =
            make_float4(a[r][0], a[r][1], a[r][2], a[r][3]);
    }
}

// One WG per batch row; 256 threads; wave w owns gate w; lane l owns h=4l..4l+3.
__global__ __launch_bounds__(256) void qlstm_kernel(
    const float* __restrict__ x,
    const unsigned int* __restrict__ WX2,
    const unsigned int* __restrict__ WH2,
    const float* __restrict__ biasc,
    const float* __restrict__ pre, int use_pre,
    const float* __restrict__ estW1, const float* __restrict__ estb1,
    const float* __restrict__ estW2, const float* __restrict__ estb2,
    const float* __restrict__ estW3, const float* __restrict__ estb3,
    float* __restrict__ out)
{
    __shared__ float combh[H_DIM];      // hx
    __shared__ float combx[D_IN];       // x(t) (fallback path only)
    __shared__ float gates[4][H_DIM];   // activated gates (pre est-scale)
    __shared__ float w1[4][8][H_DIM];   // estW1, permuted: [.][.][q*64+l] = orig h=4l+q
    __shared__ float sb1[32];
    __shared__ float sW2[128];
    __shared__ float sb2[16];
    __shared__ float sW3[16];
    __shared__ float sb3[4];
    __shared__ float escale[4];

    const int b    = blockIdx.x;
    const int tid  = threadIdx.x;
    const int w    = tid >> 6;
    const int lane = tid & 63;

    // stage est params; permute w1 so lane-l reads are stride-1 (conflict-free)
    for (int i = tid; i < 4 * 8 * H_DIM; i += 256) {
        int p = i & 255;                 // permuted pos
        int base = i & ~255;
        int h = 4 * (p & 63) + (p >> 6); // original h
        ((float*)w1)[i] = estW1[base + h];
    }
    if (tid < 32)  sb1[tid] = estb1[tid];
    if (tid < 128) sW2[tid] = estW2[tid];
    if (tid < 16)  sb2[tid] = estb2[tid];
    if (tid < 16)  sW3[tid] = estW3[tid];
    if (tid < 4)   sb3[tid] = estb3[tid];

    combh[tid] = 0.0f;
    float c_reg = 0.0f, h_reg = 0.0f;
    float4 b4 = make_float4(0.f, 0.f, 0.f, 0.f);
    if (!use_pre) b4 = ((const float4*)biasc)[tid];

    const uint4* wpx = (const uint4*)WX2;
    const uint4* wph = (const uint4*)WH2;
    const float2* ch2 = (const float2*)combh;
    const float2* cx2 = (const float2*)combx;

    __syncthreads();

    for (int t = 0; t < T_STEPS; t++) {
        float a0, a1, a2, a3;
        if (use_pre) {
            float4 p = ((const float4*)(pre + ((size_t)t * BATCH + b) * NCOL))[tid];
            a0 = p.x; a1 = p.y; a2 = p.z; a3 = p.w;
        } else {
            combx[tid] = x[((size_t)t * BATCH + b) * D_IN + tid];
            a0 = b4.x; a1 = b4.y; a2 = b4.z; a3 = b4.w;
        }
        __syncthreads();   // prev-step combh writes + combx visible

        if (!use_pre) {
            #pragma unroll 8
            for (int k2 = 0; k2 < 128; k2++) {
                uint4 wv = wpx[k2 * 256 + tid];
                float2 cv = cx2[k2];
                MAC8(wv, cv);
            }
        }
        #pragma unroll 8
        for (int k2 = 0; k2 < 128; k2++) {
            uint4 wv = wph[k2 * 256 + tid];
            float2 cv = ch2[k2];
            MAC8(wv, cv);
        }

        // activation: wave 2 (gate g) uses tanh, others sigmoid
        float v0, v1, v2, v3;
        if (w == 2) {
            v0 = tanhf_(a0); v1 = tanhf_(a1); v2 = tanhf_(a2); v3 = tanhf_(a3);
        } else {
            v0 = sigmoidf_(a0); v1 = sigmoidf_(a1); v2 = sigmoidf_(a2); v3 = sigmoidf_(a3);
        }

        // est MLP for gate w from registers: H->8 (wave-reduced) ->4 ->1
        {
            float h1[8];
            #pragma unroll
            for (int j = 0; j < 8; j++) {
                const float* wr = &w1[w][j][0];   // permuted layout
                float s = fmaf(v0, wr[lane],
                          fmaf(v1, wr[lane + 64],
                          fmaf(v2, wr[lane + 128], v3 * wr[lane + 192])));
                #pragma unroll
                for (int m = 1; m < 64; m <<= 1) s += __shfl_xor(s, m, 64);
                h1[j] = tanhf_(s + sb1[w * 8 + j]);
            }
            float h2[4];
            #pragma unroll
            for (int j = 0; j < 4; j++) {
                float s = sb2[w * 4 + j];
                #pragma unroll
                for (int q = 0; q < 8; q++) s = fmaf(h1[q], sW2[w * 32 + j * 8 + q], s);
                h2[j] = tanhf_(s);
            }
            float s3 = sb3[w];
            #pragma unroll
            for (int q = 0; q < 4; q++) s3 = fmaf(h2[q], sW3[w * 4 + q], s3);
            if (lane == 0) escale[w] = sigmoidf_(s3);
        }
        ((float4*)&gates[w][0])[lane] = make_float4(v0, v1, v2, v3);
        __syncthreads();

        // state update: thread tid owns h = tid
        const float f  = gates[0][tid] * escale[0];
        const float ii = gates[1][tid] * escale[1];
        const float g  = gates[2][tid] * escale[2];
        const float o  = gates[3][tid] * escale[3];
        c_reg = fmaf(f, c_reg, ii * g);
        h_reg = o * tanhf_(c_reg);
        combh[tid] = h_reg;
        out[((size_t)t * BATCH + b) * H_DIM + tid] = h_reg;
    }

    const size_t stacked = (size_t)T_STEPS * BATCH * H_DIM;
    out[stacked + (size_t)b * H_DIM + tid] = h_reg;
    out[stacked + (size_t)BATCH * H_DIM + (size_t)b * H_DIM + tid] = c_reg;
}

extern "C" void kernel_launch(void* const* d_in, const int* in_sizes, int n_in,
                              void* d_out, int out_size, void* d_ws, size_t ws_size,
                              hipStream_t stream) {
    const float* x     = (const float*)d_in[0];
    const float* Wf    = (const float*)d_in[1];
    const float* bf    = (const float*)d_in[2];
    const float* Wi    = (const float*)d_in[3];
    const float* bi    = (const float*)d_in[4];
    const float* Wg    = (const float*)d_in[5];
    const float* bg    = (const float*)d_in[6];
    const float* Wo    = (const float*)d_in[7];
    const float* bo    = (const float*)d_in[8];
    const float* estW1 = (const float*)d_in[9];
    const float* estb1 = (const float*)d_in[10];
    const float* estW2 = (const float*)d_in[11];
    const float* estb2 = (const float*)d_in[12];
    const float* estW3 = (const float*)d_in[13];
    const float* estb3 = (const float*)d_in[14];

    unsigned int* WX2 = (unsigned int*)d_ws;           // 128*1024 dwords = 512 KB
    unsigned int* WH2 = WX2 + 128 * 1024;              // 512 KB
    float* biasc = (float*)(WH2 + 128 * 1024);         // 4 KB
    float* pre   = biasc + NCOL;                       // [T*B][1024] fp32 = 512 MB

    const size_t need = (size_t)128 * 1024 * 4 * 2 + NCOL * 4 +
                        (size_t)T_STEPS * BATCH * NCOL * 4;
    const int use_pre = (ws_size >= need) ? 1 : 0;

    prep_kernel<<<512, 256, 0, stream>>>(Wf, Wi, Wg, Wo, bf, bi, bg, bo, WX2, WH2, biasc);
    if (use_pre) {
        pregemm_kernel<<<(T_STEPS * BATCH) / 16, 256, 0, stream>>>(x, WX2, biasc, pre);
    }
    qlstm_kernel<<<BATCH, 256, 0, stream>>>(x, WX2, WH2, biasc, pre, use_pre,
                                            estW1, estb1, estW2, estb2, estW3, estb3,
                                            (float*)d_out);
}